// Round 18
// baseline (56.761 us; speedup 1.0000x reference)
//
#include <hip/hip_runtime.h>

#define BB 4
#define TT 4096
#define CUT 2048
#define CE 1024
#define HD 64
#define QSC 0.045084220027780106f   // 1024^-0.5 * log2(e)

typedef unsigned short u16;
typedef unsigned int u32;
typedef __attribute__((ext_vector_type(8))) short bf16x8;
typedef __attribute__((ext_vector_type(4))) float f32x4;

__device__ __forceinline__ u16 f2b(float f) {
  union { float f; unsigned u; } v; v.f = f;
  unsigned r = v.u + 0x7fffu + ((v.u >> 16) & 1u);   // RNE to bf16
  return (u16)(r >> 16);
}

__device__ __forceinline__ u32 cvtpk(float lo, float hi) {
  u32 r;
  asm("v_cvt_pk_bf16_f32 %0, %1, %2" : "=v"(r) : "v"(lo), "v"(hi));
  return r;
}

// async global->LDS: per-lane 16B from g (per-lane addr), dst = uniform base + lane*16
__device__ __forceinline__ void gld16(const u16* g, u16* l) {
  __builtin_amdgcn_global_load_lds((const __attribute__((address_space(1))) u32*)g,
                                   (__attribute__((address_space(3))) u32*)l, 16, 0, 0);
}

// ---- Kernel 1: W3F = W in MFMA B-fragment order (UNCHANGED) ----
__global__ void wtrans_k(const float* __restrict__ Wk, const float* __restrict__ Wv,
                         const float* __restrict__ Wq, u16* __restrict__ w3f) {
  int id = blockIdx.x * 256 + threadIdx.x;     // 196608 total
  int j    = id & 7;
  int lane = (id >> 3) & 63;
  int f    = id >> 9;                          // 0..383
  int kstep = f & 31;
  int mnt   = f >> 5;
  int m  = mnt >> 2;
  int nt = mnt & 3;
  int k   = kstep * 32 + (lane >> 4) * 8 + j;
  int col = nt * 16 + (lane & 15);
  const float* W = (m == 0) ? Wk : (m == 1) ? Wv : Wq;
  w3f[id] = f2b(W[k * 64 + col]);
}

// ---- Kernel 2: QKV projection — round-10 best (UNCHANGED) ----
__launch_bounds__(256, 2)
__global__ void proj_k(const float* __restrict__ x, const u16* __restrict__ w3f,
                       const float* __restrict__ bk, const float* __restrict__ bv,
                       const float* __restrict__ bq,
                       u16* __restrict__ KF, u16* __restrict__ VF, u16* __restrict__ Qb) {
  __shared__ u16  st[2][2][12][512];            // [buf][half][mnt][frag] 48KB
  __shared__ f32x4 cl[2][12][64];               // K-combine 24KB
  const int tid  = threadIdx.x;
  const int lane = tid & 63;
  const int wv   = tid >> 6;                    // 0..3
  const int rg   = wv & 1;                      // row-group (16 rows)
  const int kh   = wv >> 1;                     // K-half
  const int l15  = lane & 15;
  const int g    = lane >> 4;
  const int r0   = blockIdx.x * 32;

  f32x4 acc[12];
  #pragma unroll
  for (int t = 0; t < 12; ++t) acc[t] = (f32x4){0.f, 0.f, 0.f, 0.f};

  const float* xrow = x + (size_t)(r0 + rg * 16 + l15) * CE + kh * 512;

  #define STAGE(buf, t)                                                        \
    {                                                                          \
      _Pragma("unroll")                                                        \
      for (int i = 0; i < 6; ++i) {                                            \
        int jj = wv * 6 + i;                                                   \
        int hh = jj / 12, mm = jj % 12;                                        \
        gld16(&w3f[(size_t)(mm * 32 + hh * 16 + (t)) * 512 + lane * 8],        \
              &st[buf][hh][mm][0]);                                            \
      }                                                                        \
    }

  f32x4 xs[2][2];
  STAGE(0, 0);
  __builtin_amdgcn_sched_barrier(0);
  xs[0][0] = *(const f32x4*)(xrow + g * 8);
  xs[0][1] = *(const f32x4*)(xrow + g * 8 + 4);
  asm volatile("s_waitcnt vmcnt(0)" ::: "memory");
  __builtin_amdgcn_s_barrier();

  #pragma unroll
  for (int t = 0; t < 16; ++t) {
    const int cur = t & 1, nxt = cur ^ 1;
    if (t < 15) {
      STAGE(nxt, t + 1);                        // 6 gld_lds (oldest in this batch)
      __builtin_amdgcn_sched_barrier(0);        // pin issue order: stage before x
      const float* xp = xrow + (t + 1) * 32 + g * 8;
      xs[nxt][0] = *(const f32x4*)xp;
      xs[nxt][1] = *(const f32x4*)(xp + 4);
      __builtin_amdgcn_sched_barrier(0);
    }
    bf16x8 a;
    #pragma unroll
    for (int j = 0; j < 4; ++j) {
      a[j]     = (short)f2b(xs[cur][0][j]);
      a[j + 4] = (short)f2b(xs[cur][1][j]);
    }
    #pragma unroll
    for (int mnt = 0; mnt < 12; ++mnt) {
      bf16x8 bfr = *(const bf16x8*)&st[cur][kh][mnt][lane * 8];
      acc[mnt] = __builtin_amdgcn_mfma_f32_16x16x32_bf16(a, bfr, acc[mnt], 0, 0, 0);
    }
    if (t < 15) {
      asm volatile("s_waitcnt vmcnt(2)" ::: "memory");
    } else {
      asm volatile("s_waitcnt vmcnt(0)" ::: "memory");
    }
    __builtin_amdgcn_s_barrier();
  }
  #undef STAGE

  // ---- K-half combine (cold path) ----
  if (kh == 1) {
    #pragma unroll
    for (int t = 0; t < 12; ++t) cl[rg][t][lane] = acc[t];
  }
  __syncthreads();
  if (kh == 0) {
    #pragma unroll
    for (int t = 0; t < 12; ++t) acc[t] += cl[rg][t][lane];

    const int b    = r0 >> 12;
    const int cch  = (r0 >> 6) & 63;
    const int half = (r0 >> 5) & 1;
    const int h    = rg;

    const int t0 = r0 & (TT - 1);
    if (t0 >= CUT) {
      const int trow = t0 - CUT + h * 16;
      #pragma unroll
      for (int nt = 0; nt < 4; ++nt) {
        int col = nt * 16 + l15;
        float bc = bq[col];
        #pragma unroll
        for (int r = 0; r < 4; ++r)
          Qb[((size_t)b * CUT + trow + g * 4 + r) * HD + col] =
              f2b((acc[8 + nt][r] + bc) * QSC);
      }
    }
    {
      u16* KFc = KF + ((size_t)(b * 64 + cch) * 8) * 512;
      const int kt2 = (half * 2 + h) * 2;
      #pragma unroll
      for (int nt = 0; nt < 4; ++nt) {
        int col = nt * 16 + l15;
        float bc = bk[col];
        f32x4 v = acc[nt];
        const int off = (kt2 + (nt >> 1)) * 512 + 128 * ((nt & 1) * 2 + (l15 >> 3)) + (l15 & 7);
        #pragma unroll
        for (int r = 0; r < 4; ++r)
          KFc[off + (g * 4 + r) * 8] = f2b(v[r] + bc);
      }
    }
    {
      u16* VFc = VF + ((size_t)(b * 64 + cch) * 8) * 512;
      #pragma unroll
      for (int nt = 0; nt < 4; ++nt) {
        int col = nt * 16 + l15;
        float bc = bv[col];
        f32x4 v = acc[4 + nt];
        #pragma unroll
        for (int r = 0; r < 4; ++r) {
          int tt = h * 16 + g * 4 + r;
          VFc[(half * 4 + nt) * 512 + (l15 + 16 * (tt >> 3)) * 8 + (tt & 7)] = f2b(v[r] + bc);
        }
      }
    }
  }
}

// ---- Kernel 3: attention v2. Block = 8 waves x 16 q-rows = 128 rows; chunk
// staged ONCE to LDS via global_load_lds and shared by all waves (4x less
// cache traffic, ~90 regs/wave -> 4 waves/SIMD). 4-way KV-split across blocks;
// unnormalized partials (O,l) to workspace; comb_k reduces.
__launch_bounds__(512)
__global__ void attn_k(const u16* __restrict__ Qb, const u16* __restrict__ KF,
                       const u16* __restrict__ VF, float* __restrict__ OP,
                       float* __restrict__ LP) {
  __shared__ u16 kv[2][16][512];                // [buf][frag 0-7:K, 8-15:V] 32KB
  __shared__ u32 PLd[8][16][36];                // per-wave P (bf16 pairs) 18KB
  const int tid  = threadIdx.x;
  const int lane = tid & 63;
  const int wv   = tid >> 6;                    // 0..7 = q sub-tile
  const int l15  = lane & 15;
  const int g    = lane >> 4;
  const int id   = blockIdx.x;                  // 0..255
  const int b    = id & 3;                      // XCD x -> batch x&3 (L2 locality)
  const int kvs  = (id >> 2) & 3;               // KV-split slot
  const int tile = id >> 4;                     // 0..15 (128-row q-tile)
  const int i0   = tile * 128;

  const int qmin = CUT + i0 + wv * 16;
  const int qabs = qmin + l15;

  const u16* qrow = Qb + ((size_t)b * CUT + i0 + wv * 16 + l15) * HD;
  bf16x8 qf0 = *(const bf16x8*)&qrow[g * 8];
  bf16x8 qf1 = *(const bf16x8*)&qrow[32 + g * 8];

  f32x4 o[4];
  #pragma unroll
  for (int dt = 0; dt < 4; ++dt) o[dt] = (f32x4){0.f, 0.f, 0.f, 0.f};
  float lsum = 0.f;

  const int nch = (CUT + i0 + 128) >> 6;        // 34 + 2*tile (exact)
  const u16* KFb = KF + (size_t)b * 64 * 8 * 512;
  const u16* VFb = VF + (size_t)b * 64 * 8 * 512;

  // wave wv stages frags {2wv, 2wv+1} of chunk c (1KB each, contiguous)
  #define ASTAGE(buf, c)                                                       \
    {                                                                          \
      _Pragma("unroll")                                                        \
      for (int i = 0; i < 2; ++i) {                                            \
        int f = wv * 2 + i;                                                    \
        const u16* src = (f < 8)                                               \
            ? &KFb[(size_t)(c) * 4096 + f * 512 + lane * 8]                    \
            : &VFb[(size_t)(c) * 4096 + (f - 8) * 512 + lane * 8];             \
        gld16(src, &kv[buf][f][0]);                                            \
      }                                                                        \
    }

  ASTAGE(0, kvs);
  asm volatile("s_waitcnt vmcnt(0)" ::: "memory");
  __builtin_amdgcn_s_barrier();

  int cur = 0;
  for (int c = kvs; c < nch; c += 4) {
    const int kv0 = c << 6;
    const int cn = c + 4;
    if (cn < nch) ASTAGE(cur ^ 1, cn);          // prefetch next chunk to other buf

    // ---- QK^T from LDS K-frags ----
    f32x4 st[4];
    __builtin_amdgcn_s_setprio(1);
    #pragma unroll
    for (int kt = 0; kt < 4; ++kt) {
      bf16x8 kf0 = *(const bf16x8*)&kv[cur][kt * 2 + 0][lane * 8];
      bf16x8 kf1 = *(const bf16x8*)&kv[cur][kt * 2 + 1][lane * 8];
      f32x4 s = (f32x4){0.f, 0.f, 0.f, 0.f};
      s = __builtin_amdgcn_mfma_f32_16x16x32_bf16(kf0, qf0, s, 0, 0, 0);
      s = __builtin_amdgcn_mfma_f32_16x16x32_bf16(kf1, qf1, s, 0, 0, 0);
      st[kt] = s;
    }
    __builtin_amdgcn_s_setprio(0);

    // ---- p = 2^s (fixed max; scale*log2e folded into Q) ----
    if (kv0 + 63 <= qmin) {                     // wave-uniform fully-unmasked
      #pragma unroll
      for (int kt = 0; kt < 4; ++kt)
        #pragma unroll
        for (int r = 0; r < 4; ++r) {
          float p = exp2f(st[kt][r]);
          st[kt][r] = p;
          lsum += p;
        }
    } else {
      #pragma unroll
      for (int kt = 0; kt < 4; ++kt)
        #pragma unroll
        for (int r = 0; r < 4; ++r) {
          int key = kv0 + kt * 16 + g * 4 + r;
          float p = exp2f(st[kt][r]);
          p = (key <= qabs) ? p : 0.f;
          st[kt][r] = p;
          lsum += p;
        }
    }

    #pragma unroll
    for (int kt = 0; kt < 4; ++kt) {            // pack P->bf16, wave-private LDS
      u32 d0 = cvtpk(st[kt][0], st[kt][1]);
      u32 d1 = cvtpk(st[kt][2], st[kt][3]);
      u32* p = &PLd[wv][l15][kt * 8 + g * 2];
      p[0] = d0; p[1] = d1;
    }

    // ---- O += P @ V from LDS V-frags ----
    __builtin_amdgcn_s_setprio(1);
    #pragma unroll
    for (int c2 = 0; c2 < 2; ++c2) {
      bf16x8 pa = *(const bf16x8*)&PLd[wv][l15][c2 * 16 + g * 4];
      #pragma unroll
      for (int dt = 0; dt < 4; ++dt) {
        bf16x8 vf = *(const bf16x8*)&kv[cur][8 + c2 * 4 + dt][lane * 8];
        o[dt] = __builtin_amdgcn_mfma_f32_16x16x32_bf16(pa, vf, o[dt], 0, 0, 0);
      }
    }
    __builtin_amdgcn_s_setprio(0);

    asm volatile("s_waitcnt vmcnt(0)" ::: "memory");   // staging (2/wave) done
    __builtin_amdgcn_s_barrier();
    cur ^= 1;
  }
  #undef ASTAGE

  // ---- write unnormalized partials ----
  lsum += __shfl_xor(lsum, 16);
  lsum += __shfl_xor(lsum, 32);
  float* OPb = OP + (size_t)id * 128 * 64;
  #pragma unroll
  for (int dt = 0; dt < 4; ++dt)
    #pragma unroll
    for (int r = 0; r < 4; ++r)
      OPb[(wv * 16 + g * 4 + r) * 64 + dt * 16 + l15] = o[dt][r];
  if (lane < 16) LP[(size_t)id * 128 + wv * 16 + l15] = lsum;
}

// ---- Kernel 4: combine the 4 KV-split partials and normalize ----
__global__ void comb_k(const float* __restrict__ OP, const float* __restrict__ LP,
                       float* __restrict__ out) {
  int id = blockIdx.x * 256 + threadIdx.x;     // 524288 total
  int d    = id & 63;
  int row  = (id >> 6) & 127;
  int tile = (id >> 13) & 15;
  int b    = id >> 17;                         // 0..3
  float O = 0.f, L = 0.f;
  #pragma unroll
  for (int s = 0; s < 4; ++s) {
    int bid = tile * 16 + s * 4 + b;           // matches attn_k's id decomposition
    O += OP[(size_t)bid * 8192 + row * 64 + d];
    L += LP[(size_t)bid * 128 + row];
  }
  out[((size_t)b * CUT + tile * 128 + row) * HD + d] = O / L;
}

extern "C" void kernel_launch(void* const* d_in, const int* in_sizes, int n_in,
                              void* d_out, int out_size, void* d_ws, size_t ws_size,
                              hipStream_t stream) {
  const float* x  = (const float*)d_in[0];
  const float* Wq = (const float*)d_in[1];
  const float* bq = (const float*)d_in[2];
  const float* Wk = (const float*)d_in[3];
  const float* bk = (const float*)d_in[4];
  const float* Wv = (const float*)d_in[5];
  const float* bv = (const float*)d_in[6];
  float* out = (float*)d_out;

  u16* Qb  = (u16*)d_ws;                               // [B*CUT*64] (pre-scaled)
  u16* W3F = Qb + (size_t)BB * CUT * HD;               // [384*512]  frag-ordered W
  u16* KF  = W3F + (size_t)384 * 512;                  // [B*64*8*512] frag-ordered K
  u16* VF  = KF + (size_t)BB * 64 * 8 * 512;           // [B*64*8*512] frag-ordered V
  float* OP = (float*)(VF + (size_t)BB * 64 * 8 * 512); // [256][128][64] f32 partial O
  float* LP = OP + (size_t)256 * 128 * 64;             // [256][128]     f32 partial l

  wtrans_k<<<768, 256, 0, stream>>>(Wk, Wv, Wq, W3F);
  proj_k<<<512, 256, 0, stream>>>(x, W3F, bk, bv, bq, KF, VF, Qb);
  attn_k<<<256, 512, 0, stream>>>(Qb, KF, VF, OP, LP);
  comb_k<<<2048, 256, 0, stream>>>(OP, LP, out);
}